// Round 7
// baseline (184.316 us; speedup 1.0000x reference)
//
#include <hip/hip_runtime.h>
#include <cmath>

#define EPS_BN 1e-5f

typedef __bf16 bf16;
typedef __bf16 bf16x4 __attribute__((ext_vector_type(4)));
typedef __bf16 bf16x8 __attribute__((ext_vector_type(8)));
typedef float  f32x4  __attribute__((ext_vector_type(4)));

// async global->LDS DMA, 16 B per lane, LDS dest = wave-uniform base + lane*16
__device__ __forceinline__ void dma16(const bf16* g, bf16* l) {
    __builtin_amdgcn_global_load_lds(
        (const __attribute__((address_space(1))) void*)g,
        (__attribute__((address_space(3))) void*)l, 16, 0, 0);
}

// ---------------------------------------------------------------------------
// Kernel 1: all preprocessing elementwise work in one launch. (unchanged R6)
// ---------------------------------------------------------------------------
__global__ __launch_bounds__(256) void conv_all_kernel(
    const float* __restrict__ x,
    const float* __restrict__ qdw, const float* __restrict__ qscale,
    const float* __restrict__ qbias, const float* __restrict__ qmean,
    const float* __restrict__ qvar,
    const float* __restrict__ kdw, const float* __restrict__ kscale,
    const float* __restrict__ kbias, const float* __restrict__ kmean,
    const float* __restrict__ kvar,
    const float* __restrict__ vdw, const float* __restrict__ vscale,
    const float* __restrict__ vbias, const float* __restrict__ vmean,
    const float* __restrict__ vvar,
    const float* __restrict__ qpw, const float* __restrict__ kpw,
    const float* __restrict__ vpw,
    bf16* __restrict__ qhi, bf16* __restrict__ qlo,
    bf16* __restrict__ khi, bf16* __restrict__ klo,
    bf16* __restrict__ vhi, bf16* __restrict__ vlo,
    bf16* __restrict__ wt) {
    const int WW = 56, C = 192;
    int bid = blockIdx.x;

    if (bid < 4704) {
        int idx = bid * 256 + threadIdx.x;
        int p  = idx / 48;
        int c4 = (idx - p * 48) * 4;
        int b  = p / 3136;
        int rem = p - b * 3136;
        int oy = rem / 56;
        int ox = rem - oy * 56;
        const float* xb = x + (size_t)b * 3136 * C;

        float4 sc = *(const float4*)&qscale[c4];
        float4 vr = *(const float4*)&qvar[c4];
        float4 bi = *(const float4*)&qbias[c4];
        float4 mn = *(const float4*)&qmean[c4];
        float aA[4] = {sc.x * rsqrtf(vr.x + EPS_BN), sc.y * rsqrtf(vr.y + EPS_BN),
                       sc.z * rsqrtf(vr.z + EPS_BN), sc.w * rsqrtf(vr.w + EPS_BN)};
        float aB[4] = {bi.x - mn.x * aA[0], bi.y - mn.y * aA[1],
                       bi.z - mn.z * aA[2], bi.w - mn.w * aA[3]};
        float s[4] = {0.f, 0.f, 0.f, 0.f};
#pragma unroll
        for (int ky = 0; ky < 3; ky++) {
            int iy = oy + ky - 1;
            bool yok = (iy >= 0) && (iy < 56);
#pragma unroll
            for (int kx = 0; kx < 3; kx++) {
                int ix = ox + kx - 1;
                if (yok && ix >= 0 && ix < WW) {
                    float4 xv = *(const float4*)&xb[((size_t)iy * WW + ix) * C + c4];
                    float4 wv = *(const float4*)&qdw[(ky * 3 + kx) * C + c4];
                    s[0] += xv.x * wv.x; s[1] += xv.y * wv.y;
                    s[2] += xv.z * wv.z; s[3] += xv.w * wv.w;
                }
            }
        }
        bf16x4 hv, lv;
#pragma unroll
        for (int j = 0; j < 4; j++) {
            float av = s[j] * aA[j] + aB[j];
            bf16 hh = (bf16)av;
            hv[j] = hh;
            lv[j] = (bf16)(av - (float)hh);
        }
        *(bf16x4*)&qhi[(size_t)p * C + c4] = hv;
        *(bf16x4*)&qlo[(size_t)p * C + c4] = lv;
    } else if (bid < 5880) {
        int idx = (bid - 4704) * 256 + threadIdx.x;
        int p  = idx / 48;
        int c4 = (idx - p * 48) * 4;
        int b  = p / 784;
        int rem = p - b * 784;
        int oy = rem / 28;
        int ox = rem - oy * 28;
        const float* xb = x + (size_t)b * 3136 * C;

        float ks[4] = {0.f, 0.f, 0.f, 0.f};
        float vs[4] = {0.f, 0.f, 0.f, 0.f};
#pragma unroll
        for (int ky = 0; ky < 3; ky++) {
            int iy = oy * 2 + ky;
            bool yok = iy < 56;
#pragma unroll
            for (int kx = 0; kx < 3; kx++) {
                int ix = ox * 2 + kx;
                if (yok && ix < WW) {
                    float4 xv = *(const float4*)&xb[((size_t)iy * WW + ix) * C + c4];
                    float4 kw = *(const float4*)&kdw[(ky * 3 + kx) * C + c4];
                    float4 vw = *(const float4*)&vdw[(ky * 3 + kx) * C + c4];
                    ks[0] += xv.x * kw.x; ks[1] += xv.y * kw.y;
                    ks[2] += xv.z * kw.z; ks[3] += xv.w * kw.w;
                    vs[0] += xv.x * vw.x; vs[1] += xv.y * vw.y;
                    vs[2] += xv.z * vw.z; vs[3] += xv.w * vw.w;
                }
            }
        }
        float4 ksc = *(const float4*)&kscale[c4];
        float4 kvr = *(const float4*)&kvar[c4];
        float4 kbi = *(const float4*)&kbias[c4];
        float4 kmn = *(const float4*)&kmean[c4];
        float4 vsc = *(const float4*)&vscale[c4];
        float4 vvr = *(const float4*)&vvar[c4];
        float4 vbi = *(const float4*)&vbias[c4];
        float4 vmn = *(const float4*)&vmean[c4];
        float kA[4] = {ksc.x * rsqrtf(kvr.x + EPS_BN), ksc.y * rsqrtf(kvr.y + EPS_BN),
                       ksc.z * rsqrtf(kvr.z + EPS_BN), ksc.w * rsqrtf(kvr.w + EPS_BN)};
        float kB[4] = {kbi.x - kmn.x * kA[0], kbi.y - kmn.y * kA[1],
                       kbi.z - kmn.z * kA[2], kbi.w - kmn.w * kA[3]};
        float vA[4] = {vsc.x * rsqrtf(vvr.x + EPS_BN), vsc.y * rsqrtf(vvr.y + EPS_BN),
                       vsc.z * rsqrtf(vvr.z + EPS_BN), vsc.w * rsqrtf(vvr.w + EPS_BN)};
        float vB[4] = {vbi.x - vmn.x * vA[0], vbi.y - vmn.y * vA[1],
                       vbi.z - vmn.z * vA[2], vbi.w - vmn.w * vA[3]};
        bf16x4 kh, kl, vh, vl;
#pragma unroll
        for (int j = 0; j < 4; j++) {
            float kf = ks[j] * kA[j] + kB[j];
            float vf = vs[j] * vA[j] + vB[j];
            bf16 h1 = (bf16)kf; kh[j] = h1; kl[j] = (bf16)(kf - (float)h1);
            bf16 h2 = (bf16)vf; vh[j] = h2; vl[j] = (bf16)(vf - (float)h2);
        }
        *(bf16x4*)&khi[(size_t)p * C + c4] = kh;
        *(bf16x4*)&klo[(size_t)p * C + c4] = kl;
        *(bf16x4*)&vhi[(size_t)p * C + c4] = vh;
        *(bf16x4*)&vlo[(size_t)p * C + c4] = vl;
    } else {
        int idx = (bid - 5880) * 256 + threadIdx.x;
        if (idx < 3 * 36864) {
            int mat = idx / 36864, r = idx % 36864;
            int n = r / 192, k = r - n * 192;
            const float* src = (mat == 0) ? qpw : (mat == 1) ? kpw : vpw;
            wt[idx] = (bf16)src[k * 192 + n];
        }
    }
}

// ---------------------------------------------------------------------------
// Kernel 2: pointwise GEMMs, N split in two, Ws[96][200] = 38.4 KB.
// (unchanged R10-R12)
// ---------------------------------------------------------------------------
__global__ __launch_bounds__(256) void gemm_all_kernel(
    const bf16* __restrict__ qhi, const bf16* __restrict__ qlo,
    const bf16* __restrict__ khi, const bf16* __restrict__ klo,
    const bf16* __restrict__ vhi, const bf16* __restrict__ vlo,
    const bf16* __restrict__ wt,
    bf16* __restrict__ qbuf, bf16* __restrict__ kbuf, bf16* __restrict__ vtbuf) {
    __shared__ bf16 Ws[96][200];
    int t = threadIdx.x;
    int bid = blockIdx.x;

    int mode, mt, nh;
    const bf16 *Ahi, *Alo, *Wsrc;
    if (bid < 784)      { mode = 0; mt = bid >> 1;         nh = bid & 1;
                          Ahi = qhi; Alo = qlo; Wsrc = wt; }
    else if (bid < 980) { mode = 1; int r = bid - 784; mt = r >> 1; nh = r & 1;
                          Ahi = khi; Alo = klo; Wsrc = wt + 36864; }
    else                { mode = 2; int r = bid - 980; mt = r >> 1; nh = r & 1;
                          Ahi = vhi; Alo = vlo; Wsrc = wt + 73728; }
    int n0 = nh * 96;

#pragma unroll
    for (int it = 0; it < 9; it++) {
        int idx = it * 256 + t;
        int n = idx / 24, ck = idx - n * 24;
        *(uint4*)&Ws[n][ck * 8] = *(const uint4*)&Wsrc[(size_t)(n0 + n) * 192 + ck * 8];
    }
    __syncthreads();

    int lane = t & 63, wid = t >> 6;
    int l16 = lane & 15, quad = lane >> 4;
    int wrow = wid * 16;
    int m0 = mt * 64;

    f32x4 acc[6];
#pragma unroll
    for (int n = 0; n < 6; n++) acc[n] = f32x4{0.f, 0.f, 0.f, 0.f};

    const bf16* arh = Ahi + (size_t)(m0 + wrow + l16) * 192;
    const bf16* arl = Alo + (size_t)(m0 + wrow + l16) * 192;
#pragma unroll
    for (int kc = 0; kc < 6; kc++) {
        bf16x8 ah = *(const bf16x8*)(arh + kc * 32 + quad * 8);
        bf16x8 al = *(const bf16x8*)(arl + kc * 32 + quad * 8);
#pragma unroll
        for (int n = 0; n < 6; n++) {
            bf16x8 bfr = *(const bf16x8*)&Ws[n * 16 + l16][kc * 32 + quad * 8];
            acc[n] = __builtin_amdgcn_mfma_f32_16x16x32_bf16(al, bfr, acc[n], 0, 0, 0);
            acc[n] = __builtin_amdgcn_mfma_f32_16x16x32_bf16(ah, bfr, acc[n], 0, 0, 0);
        }
    }

    if (mode == 2) {
#pragma unroll
        for (int reg = 0; reg < 4; reg++) {
            int row = m0 + wrow + quad * 4 + reg;
            int b = row / 784;
            int loc = row - b * 784;
#pragma unroll
            for (int n = 0; n < 6; n++) {
                int col = n0 + n * 16 + l16;
                int h = col >> 6, d = col & 63;
                vtbuf[(((size_t)b * 3 + h) * 64 + d) * 784 + loc] = (bf16)acc[n][reg];
            }
        }
    } else {
        bf16* outp = (mode == 0) ? qbuf : kbuf;
        const float s = (mode == 0) ? 0.125f : 1.0f;
#pragma unroll
        for (int reg = 0; reg < 4; reg++) {
            size_t row = m0 + wrow + quad * 4 + reg;
#pragma unroll
            for (int n = 0; n < 6; n++)
                outp[row * 192 + n0 + n * 16 + l16] = (bf16)(acc[n][reg] * s);
        }
    }
}

// ---------------------------------------------------------------------------
// Kernel 3: flash attention. R13: BK 112 -> 80 so LDS fits 4 blocks/CU.
// R12 validated the occupancy lever (2->3 blocks/CU: 44 -> ~36 us); this is
// the next notch: Ks[2][80][64]=20480 + Vts[64][104]=13312 + Ps[64][40]=5120
// = 38912 B <= 40960 -> 4 blocks/CU = 16 waves/CU.
//  - Ks: XOR chunk swizzle unchanged (row&7 == l16&7 still holds at BK=80).
//  - Vts: 96 keys padded (80 real + 16 zero-P), 12 data chunks + 1 PAD chunk
//    per row (pad-based conflict fix; 12 chunks can't XOR-swizzle). Start-bank
//    pattern = 2-way (free, m136). Linear DMA dest; source mapping via /13.
//  - Ps: per-32-key PV step relayout ([64][40], 3 steps/chunk). Wave-local
//    write->read, in-order LDS pipe; step 2 writes the zero pad. No init.
//  - 10 chunks of 80 keys; last chunk has 64 real keys -> tile 4 masked to
//    -1e30 after QK^T (P=0). Garbage DMA reads land in adjacent workspace
//    buffers (kbuf->vtbuf->wt), finite, annihilated by zero-P.
//  - Counted-vmcnt schedule (R11/R12-validated): V issued first (13 stripes,
//    4/3/3/3), K[c+1] second (10 stripes, 3/3/2/2); after softmax wait
//    vmcnt(ownK)=3/3/2/2 + raw s_barrier + sched_barrier; K never drained
//    mid-chunk; end-of-chunk __syncthreads drains K (whole chunk in flight).
//  - s_setprio(1/0) around MFMA clusters (T5: meaningful with 4 phase-
//    diverse blocks/CU).
// waves_per_eu(4,4): 128-VGPR budget for 4 waves/SIMD (est. ~110 live).
// ---------------------------------------------------------------------------
__global__ __launch_bounds__(256)
__attribute__((amdgpu_waves_per_eu(4, 4)))
void attn3_kernel(const bf16* __restrict__ qb,
                  const bf16* __restrict__ kb,
                  const bf16* __restrict__ vtb,
                  float* __restrict__ out) {
    const int LQ = 3136, LK = 784, C = 192;
    int qt = blockIdx.x, h = blockIdx.y, b = blockIdx.z;

    __shared__ bf16 Ks[2][5120];   // [buf][80][64], XOR-swizzled 16B chunks
    __shared__ bf16 Vts[6656];     // [64][104]: 12 data chunks + 1 pad / row
    __shared__ bf16 Ps[2560];      // [64][40]: per-kk-step P relayout

    int t    = threadIdx.x;
    int lane = t & 63;
    int wid  = t >> 6;
    int l16  = lane & 15;
    int quad = lane >> 4;
    int wrow = wid * 16;
    int l7   = l16 & 7;

    const bf16* kbase  = kb + (size_t)b * LK * C + h * 64;
    const bf16* vtbase = vtb + ((size_t)(b * 3 + h)) * 64 * LK;

    // K DMA source swizzle: stripe s covers rows s*8+(lane>>3); physical
    // chunk (lane&7) holds logical chunk (lane&7)^(lane>>3).
    const bf16* ksrc = kbase + (lane >> 3) * C + (((lane & 7) ^ (lane >> 3)) * 8);

    // Vt DMA source offsets: dest chunk jc = s*64+lane -> row jc/13,
    // cc = jc%13; cc<10 real (key cc*8), cc>=10 pad (finite garbage).
    int voff[4];
#pragma unroll
    for (int i = 0; i < 4; i++) {
        int s = wid + 4 * i;
        int jc = s * 64 + lane;
        int row = jc / 13;
        int cc = jc - row * 13;
        int key8 = (cc < 10) ? cc * 8 : 72;
        voff[i] = (s < 13) ? (row * LK + key8) : 0;
    }

    // prologue: chunk-0 K DMA (10 stripes, 3/3/2/2 per wave)
    for (int s = wid; s < 10; s += 4)
        dma16(ksrc + s * 8 * C, &Ks[0][s * 512]);

    // Q fragments (B operand: n = q = l16, k = d) held in registers
    bf16x8 qfrag[2];
    {
        const bf16* qrow = qb + ((size_t)b * LQ + qt * 64 + wrow + l16) * C + h * 64;
        qfrag[0] = *(const bf16x8*)(qrow + quad * 8);
        qfrag[1] = *(const bf16x8*)(qrow + 32 + quad * 8);
    }

    // per-lane Ks read offsets (elements) for kk=0,1: physical chunk XOR
    int kA0 = l16 * 64 + (((quad    ) ^ l7) * 8);
    int kA1 = l16 * 64 + (((quad + 4) ^ l7) * 8);
    int prow = (wrow + l16) * 40;   // Ps row base (elements)

    float m_run = -INFINITY, l_run = 0.f;
    f32x4 o_acc[4];
#pragma unroll
    for (int dt = 0; dt < 4; dt++) o_acc[dt] = f32x4{0.f, 0.f, 0.f, 0.f};

    __syncthreads();   // drains prologue DMA -> Ks[0] visible

    for (int c = 0; c < 10; c++) {
        const int cur = c & 1, nxt = cur ^ 1;
        const int j0 = c * 80;

        // 1. Vt[c] DMA: 13 stripes (4/3/3/3 per wave), oldest in queue
#pragma unroll
        for (int i = 0; i < 4; i++) {
            int s = wid + 4 * i;
            if (s < 13) dma16(vtbase + j0 + voff[i], Vts + s * 512);
        }
        __builtin_amdgcn_sched_barrier(0);   // V issues stay before K issues

        // 2. K[c+1] DMA into the other buffer (3/3/2/2 per wave)
        if (c < 9) {
            const bf16* kn = ksrc + (size_t)(c + 1) * 80 * C;
            for (int s = wid; s < 10; s += 4)
                dma16(kn + s * 8 * C, &Ks[nxt][s * 512]);
        }
        __builtin_amdgcn_sched_barrier(0);   // keep issue groups intact

        // 3. S^T = K Q^T : 5 key-tiles x (K-dim 64 = 2 steps), K from LDS
        f32x4 st[5];
#pragma unroll
        for (int kb5 = 0; kb5 < 5; kb5++) st[kb5] = f32x4{0.f, 0.f, 0.f, 0.f};
        __builtin_amdgcn_s_setprio(1);
#pragma unroll
        for (int kk = 0; kk < 2; kk++) {
            int kA = (kk == 0) ? kA0 : kA1;
#pragma unroll
            for (int kb5 = 0; kb5 < 5; kb5++) {
                bf16x8 afrag = *(const bf16x8*)&Ks[cur][kb5 * 1024 + kA];
                st[kb5] = __builtin_amdgcn_mfma_f32_16x16x32_bf16(afrag, qfrag[kk], st[kb5], 0, 0, 0);
            }
        }
        __builtin_amdgcn_s_setprio(0);

        // 3b. last chunk has 64 real keys: mask tile 4 (keys 784..799)
        if (c == 9) st[4] = f32x4{-1e30f, -1e30f, -1e30f, -1e30f};

        // 4. online softmax for q = l16 (20 keys in-lane, cross-quad shuffles)
        float mx = -INFINITY;
#pragma unroll
        for (int kb5 = 0; kb5 < 5; kb5++)
#pragma unroll
            for (int r = 0; r < 4; r++) mx = fmaxf(mx, st[kb5][r]);
        mx = fmaxf(mx, __shfl_xor(mx, 16, 64));
        mx = fmaxf(mx, __shfl_xor(mx, 32, 64));
        float m_new = fmaxf(m_run, mx);
        float alpha = __expf(m_run - m_new);   // chunk 0: exp(-inf)=0

        float rs = 0.f;
        bf16x4 pk[5];                           // static indices only
#pragma unroll
        for (int kb5 = 0; kb5 < 5; kb5++) {
            bf16x4 pv;
#pragma unroll
            for (int r = 0; r < 4; r++) {
                float p = __expf(st[kb5][r] - m_new);
                rs += p;
                pv[r] = (bf16)p;
            }
            pk[kb5] = pv;
        }
        rs += __shfl_xor(rs, 16, 64);
        rs += __shfl_xor(rs, 32, 64);
        l_run = l_run * alpha + rs;
        m_run = m_new;
#pragma unroll
        for (int dt = 0; dt < 4; dt++)
#pragma unroll
            for (int r = 0; r < 4; r++) o_acc[dt][r] *= alpha;

        // 5. counted wait: own Vt stripes retired when outstanding == own K
        //    count (vmcnt retires in order); raw barrier extends to all waves
        if (c < 9) {
            if (wid < 2) asm volatile("s_waitcnt vmcnt(3)" ::: "memory");
            else         asm volatile("s_waitcnt vmcnt(2)" ::: "memory");
        } else {
            asm volatile("s_waitcnt vmcnt(0)" ::: "memory");
        }
        __builtin_amdgcn_s_barrier();
        __builtin_amdgcn_sched_barrier(0);   // no Vts reads above this point

        // 6. PV: 3 steps of 32 keys; per-step wave-local P relayout via Ps
        bf16x4 zv = {(bf16)0.f, (bf16)0.f, (bf16)0.f, (bf16)0.f};
#pragma unroll
        for (int kk = 0; kk < 3; kk++) {
            bf16x4 w1;
            if (kk == 0)      w1 = pk[1];
            else if (kk == 1) w1 = pk[3];
            else              w1 = zv;          // pad keys 80..95: P = 0
            *(bf16x4*)&Ps[prow + quad * 4]      = pk[2 * kk];
            *(bf16x4*)&Ps[prow + 16 + quad * 4] = w1;
            bf16x8 pfrag = *(const bf16x8*)&Ps[prow + quad * 8];
            __builtin_amdgcn_s_setprio(1);
#pragma unroll
            for (int dt = 0; dt < 4; dt++) {
                bf16x8 vfrag = *(const bf16x8*)&Vts[(dt * 16 + l16) * 104
                                                   + (kk * 4 + quad) * 8];
                o_acc[dt] = __builtin_amdgcn_mfma_f32_16x16x32_bf16(vfrag, pfrag, o_acc[dt], 0, 0, 0);
            }
            __builtin_amdgcn_s_setprio(0);
        }

        // 7. end-of-chunk barrier: drains K[c+1] DMA (whole chunk in flight),
        //    orders Ks[cur]/Vts/Ps reads vs next chunk's writes.
        __syncthreads();
    }

    // epilogue: lane holds q = l16, d = dt*16 + quad*4 + reg -> float4 stores
    float invl = 1.f / l_run;
    float* ob = out + ((size_t)b * LQ + qt * 64 + wrow + l16) * C + h * 64;
#pragma unroll
    for (int dt = 0; dt < 4; dt++) {
        float4 v4 = {o_acc[dt][0] * invl, o_acc[dt][1] * invl,
                     o_acc[dt][2] * invl, o_acc[dt][3] * invl};
        *(float4*)(ob + dt * 16 + quad * 4) = v4;
    }
}

// ---------------------------------------------------------------------------
extern "C" void kernel_launch(void* const* d_in, const int* in_sizes, int n_in,
                              void* d_out, int out_size, void* d_ws, size_t ws_size,
                              hipStream_t stream) {
    const float* x = (const float*)d_in[0];

    const float* q_dw = (const float*)d_in[1];
    const float* q_scale = (const float*)d_in[2];
    const float* q_bias = (const float*)d_in[3];
    const float* q_mean = (const float*)d_in[4];
    const float* q_var = (const float*)d_in[5];
    const float* q_pw = (const float*)d_in[6];

    const float* k_dw = (const float*)d_in[7];
    const float* k_scale = (const float*)d_in[8];
    const float* k_bias = (const float*)d_in[9];
    const float* k_mean = (const float*)d_in[10];
    const float* k_var = (const float*)d_in[11];
    const float* k_pw = (const float*)d_in[12];

    const float* v_dw = (const float*)d_in[13];
    const float* v_scale = (const float*)d_in[14];
    const float* v_bias = (const float*)d_in[15];
    const float* v_mean = (const float*)d_in[16];
    const float* v_var = (const float*)d_in[17];
    const float* v_pw = (const float*)d_in[18];

    float* out = (float*)d_out;

    // workspace layout (bytes, all 16B aligned)
    char* ws = (char*)d_ws;
    bf16* qhi = (bf16*)(ws);                  // 9,633,792
    bf16* qlo = (bf16*)(ws + 9633792);        // 9,633,792
    bf16* khi = (bf16*)(ws + 19267584);       // 2,408,448
    bf16* klo = (bf16*)(ws + 21676032);       // 2,408,448
    bf16* vhi = (bf16*)(ws + 24084480);       // 2,408,448
    bf16* vlo = (bf16*)(ws + 26492928);       // 2,408,448
    bf16* qbuf = (bf16*)(ws + 28901376);      // 9,633,792
    bf16* kbuf = (bf16*)(ws + 38535168);      // 2,408,448
    bf16* vtbuf = (bf16*)(ws + 40943616);     // 2,408,448
    bf16* wt = (bf16*)(ws + 43352064);        // 221,184

    // stage 1: conv(Q) + conv(K,V) + weight cast, one launch (6312 blocks)
    conv_all_kernel<<<6312, 256, 0, stream>>>(
        x,
        q_dw, q_scale, q_bias, q_mean, q_var,
        k_dw, k_scale, k_bias, k_mean, k_var,
        v_dw, v_scale, v_bias, v_mean, v_var,
        q_pw, k_pw, v_pw,
        qhi, qlo, khi, klo, vhi, vlo, wt);

    // stage 2: all three pointwise GEMMs, one launch (1176 blocks, N split)
    gemm_all_kernel<<<1176, 256, 0, stream>>>(
        qhi, qlo, khi, klo, vhi, vlo, wt, qbuf, kbuf, vtbuf);

    // stage 3: attention (49 q-tiles, 3 heads, 8 batches)
    attn3_kernel<<<dim3(49, 3, 8), 256, 0, stream>>>(qbuf, kbuf, vtbuf, out);
}

// Round 8
// 174.526 us; speedup vs baseline: 1.0561x; 1.0561x over previous
//
#include <hip/hip_runtime.h>
#include <cmath>

#define EPS_BN 1e-5f

typedef __bf16 bf16;
typedef __bf16 bf16x4 __attribute__((ext_vector_type(4)));
typedef __bf16 bf16x8 __attribute__((ext_vector_type(8)));
typedef float  f32x4  __attribute__((ext_vector_type(4)));

// async global->LDS DMA, 16 B per lane, LDS dest = wave-uniform base + lane*16
__device__ __forceinline__ void dma16(const bf16* g, bf16* l) {
    __builtin_amdgcn_global_load_lds(
        (const __attribute__((address_space(1))) void*)g,
        (__attribute__((address_space(3))) void*)l, 16, 0, 0);
}

// raw v_exp_f32: D = 2^S0 (one transcendental op, no pre-multiply)
__device__ __forceinline__ float exp2_hw(float x) {
    float r;
    asm("v_exp_f32 %0, %1" : "=v"(r) : "v"(x));
    return r;
}

// ---------------------------------------------------------------------------
// Kernel 1: all preprocessing elementwise work in one launch. (unchanged R6)
// ---------------------------------------------------------------------------
__global__ __launch_bounds__(256) void conv_all_kernel(
    const float* __restrict__ x,
    const float* __restrict__ qdw, const float* __restrict__ qscale,
    const float* __restrict__ qbias, const float* __restrict__ qmean,
    const float* __restrict__ qvar,
    const float* __restrict__ kdw, const float* __restrict__ kscale,
    const float* __restrict__ kbias, const float* __restrict__ kmean,
    const float* __restrict__ kvar,
    const float* __restrict__ vdw, const float* __restrict__ vscale,
    const float* __restrict__ vbias, const float* __restrict__ vmean,
    const float* __restrict__ vvar,
    const float* __restrict__ qpw, const float* __restrict__ kpw,
    const float* __restrict__ vpw,
    bf16* __restrict__ qhi, bf16* __restrict__ qlo,
    bf16* __restrict__ khi, bf16* __restrict__ klo,
    bf16* __restrict__ vhi, bf16* __restrict__ vlo,
    bf16* __restrict__ wt) {
    const int WW = 56, C = 192;
    int bid = blockIdx.x;

    if (bid < 4704) {
        int idx = bid * 256 + threadIdx.x;
        int p  = idx / 48;
        int c4 = (idx - p * 48) * 4;
        int b  = p / 3136;
        int rem = p - b * 3136;
        int oy = rem / 56;
        int ox = rem - oy * 56;
        const float* xb = x + (size_t)b * 3136 * C;

        float4 sc = *(const float4*)&qscale[c4];
        float4 vr = *(const float4*)&qvar[c4];
        float4 bi = *(const float4*)&qbias[c4];
        float4 mn = *(const float4*)&qmean[c4];
        float aA[4] = {sc.x * rsqrtf(vr.x + EPS_BN), sc.y * rsqrtf(vr.y + EPS_BN),
                       sc.z * rsqrtf(vr.z + EPS_BN), sc.w * rsqrtf(vr.w + EPS_BN)};
        float aB[4] = {bi.x - mn.x * aA[0], bi.y - mn.y * aA[1],
                       bi.z - mn.z * aA[2], bi.w - mn.w * aA[3]};
        float s[4] = {0.f, 0.f, 0.f, 0.f};
#pragma unroll
        for (int ky = 0; ky < 3; ky++) {
            int iy = oy + ky - 1;
            bool yok = (iy >= 0) && (iy < 56);
#pragma unroll
            for (int kx = 0; kx < 3; kx++) {
                int ix = ox + kx - 1;
                if (yok && ix >= 0 && ix < WW) {
                    float4 xv = *(const float4*)&xb[((size_t)iy * WW + ix) * C + c4];
                    float4 wv = *(const float4*)&qdw[(ky * 3 + kx) * C + c4];
                    s[0] += xv.x * wv.x; s[1] += xv.y * wv.y;
                    s[2] += xv.z * wv.z; s[3] += xv.w * wv.w;
                }
            }
        }
        bf16x4 hv, lv;
#pragma unroll
        for (int j = 0; j < 4; j++) {
            float av = s[j] * aA[j] + aB[j];
            bf16 hh = (bf16)av;
            hv[j] = hh;
            lv[j] = (bf16)(av - (float)hh);
        }
        *(bf16x4*)&qhi[(size_t)p * C + c4] = hv;
        *(bf16x4*)&qlo[(size_t)p * C + c4] = lv;
    } else if (bid < 5880) {
        int idx = (bid - 4704) * 256 + threadIdx.x;
        int p  = idx / 48;
        int c4 = (idx - p * 48) * 4;
        int b  = p / 784;
        int rem = p - b * 784;
        int oy = rem / 28;
        int ox = rem - oy * 28;
        const float* xb = x + (size_t)b * 3136 * C;

        float ks[4] = {0.f, 0.f, 0.f, 0.f};
        float vs[4] = {0.f, 0.f, 0.f, 0.f};
#pragma unroll
        for (int ky = 0; ky < 3; ky++) {
            int iy = oy * 2 + ky;
            bool yok = iy < 56;
#pragma unroll
            for (int kx = 0; kx < 3; kx++) {
                int ix = ox * 2 + kx;
                if (yok && ix < WW) {
                    float4 xv = *(const float4*)&xb[((size_t)iy * WW + ix) * C + c4];
                    float4 kw = *(const float4*)&kdw[(ky * 3 + kx) * C + c4];
                    float4 vw = *(const float4*)&vdw[(ky * 3 + kx) * C + c4];
                    ks[0] += xv.x * kw.x; ks[1] += xv.y * kw.y;
                    ks[2] += xv.z * kw.z; ks[3] += xv.w * kw.w;
                    vs[0] += xv.x * vw.x; vs[1] += xv.y * vw.y;
                    vs[2] += xv.z * vw.z; vs[3] += xv.w * vw.w;
                }
            }
        }
        float4 ksc = *(const float4*)&kscale[c4];
        float4 kvr = *(const float4*)&kvar[c4];
        float4 kbi = *(const float4*)&kbias[c4];
        float4 kmn = *(const float4*)&kmean[c4];
        float4 vsc = *(const float4*)&vscale[c4];
        float4 vvr = *(const float4*)&vvar[c4];
        float4 vbi = *(const float4*)&vbias[c4];
        float4 vmn = *(const float4*)&vmean[c4];
        float kA[4] = {ksc.x * rsqrtf(kvr.x + EPS_BN), ksc.y * rsqrtf(kvr.y + EPS_BN),
                       ksc.z * rsqrtf(kvr.z + EPS_BN), ksc.w * rsqrtf(kvr.w + EPS_BN)};
        float kB[4] = {kbi.x - kmn.x * kA[0], kbi.y - kmn.y * kA[1],
                       kbi.z - kmn.z * kA[2], kbi.w - kmn.w * kA[3]};
        float vA[4] = {vsc.x * rsqrtf(vvr.x + EPS_BN), vsc.y * rsqrtf(vvr.y + EPS_BN),
                       vsc.z * rsqrtf(vvr.z + EPS_BN), vsc.w * rsqrtf(vvr.w + EPS_BN)};
        float vB[4] = {vbi.x - vmn.x * vA[0], vbi.y - vmn.y * vA[1],
                       vbi.z - vmn.z * vA[2], vbi.w - vmn.w * vA[3]};
        bf16x4 kh, kl, vh, vl;
#pragma unroll
        for (int j = 0; j < 4; j++) {
            float kf = ks[j] * kA[j] + kB[j];
            float vf = vs[j] * vA[j] + vB[j];
            bf16 h1 = (bf16)kf; kh[j] = h1; kl[j] = (bf16)(kf - (float)h1);
            bf16 h2 = (bf16)vf; vh[j] = h2; vl[j] = (bf16)(vf - (float)h2);
        }
        *(bf16x4*)&khi[(size_t)p * C + c4] = kh;
        *(bf16x4*)&klo[(size_t)p * C + c4] = kl;
        *(bf16x4*)&vhi[(size_t)p * C + c4] = vh;
        *(bf16x4*)&vlo[(size_t)p * C + c4] = vl;
    } else {
        int idx = (bid - 5880) * 256 + threadIdx.x;
        if (idx < 3 * 36864) {
            int mat = idx / 36864, r = idx % 36864;
            int n = r / 192, k = r - n * 192;
            const float* src = (mat == 0) ? qpw : (mat == 1) ? kpw : vpw;
            wt[idx] = (bf16)src[k * 192 + n];
        }
    }
}

// ---------------------------------------------------------------------------
// Kernel 2: pointwise GEMMs, N split in two, Ws[96][200] = 38.4 KB.
// R14 changes:
//  - mode 0 scale folds log2(e): 0.125 * 1.4426950 = 0.18033688 (attn
//    softmax now uses raw v_exp_f32 = 2^x, no per-element pre-multiply).
//  - mode 2 uses SWAPPED MFMA operands: mfma(bfr, a) transposes the output
//    fragment in-register (A/B fragment layouts are identical for 16x16x32),
//    so lane l16 indexes 16 CONSECUTIVE loc values -> each quarter-wave's
//    vtbuf store is one contiguous 32B segment instead of 16 scattered 2B
//    stores at stride 1568B. Zero LDS, same instruction count.
// ---------------------------------------------------------------------------
__global__ __launch_bounds__(256) void gemm_all_kernel(
    const bf16* __restrict__ qhi, const bf16* __restrict__ qlo,
    const bf16* __restrict__ khi, const bf16* __restrict__ klo,
    const bf16* __restrict__ vhi, const bf16* __restrict__ vlo,
    const bf16* __restrict__ wt,
    bf16* __restrict__ qbuf, bf16* __restrict__ kbuf, bf16* __restrict__ vtbuf) {
    __shared__ bf16 Ws[96][200];
    int t = threadIdx.x;
    int bid = blockIdx.x;

    int mode, mt, nh;
    const bf16 *Ahi, *Alo, *Wsrc;
    if (bid < 784)      { mode = 0; mt = bid >> 1;         nh = bid & 1;
                          Ahi = qhi; Alo = qlo; Wsrc = wt; }
    else if (bid < 980) { mode = 1; int r = bid - 784; mt = r >> 1; nh = r & 1;
                          Ahi = khi; Alo = klo; Wsrc = wt + 36864; }
    else                { mode = 2; int r = bid - 980; mt = r >> 1; nh = r & 1;
                          Ahi = vhi; Alo = vlo; Wsrc = wt + 73728; }
    int n0 = nh * 96;

#pragma unroll
    for (int it = 0; it < 9; it++) {
        int idx = it * 256 + t;
        int n = idx / 24, ck = idx - n * 24;
        *(uint4*)&Ws[n][ck * 8] = *(const uint4*)&Wsrc[(size_t)(n0 + n) * 192 + ck * 8];
    }
    __syncthreads();

    int lane = t & 63, wid = t >> 6;
    int l16 = lane & 15, quad = lane >> 4;
    int wrow = wid * 16;
    int m0 = mt * 64;

    f32x4 acc[6];
#pragma unroll
    for (int n = 0; n < 6; n++) acc[n] = f32x4{0.f, 0.f, 0.f, 0.f};

    const bf16* arh = Ahi + (size_t)(m0 + wrow + l16) * 192;
    const bf16* arl = Alo + (size_t)(m0 + wrow + l16) * 192;

    if (mode == 2) {
        // swapped operands: D[w][pixel] — lane holds pixel = wrow+l16,
        // weight col = n*16 + quad*4 + reg
#pragma unroll
        for (int kc = 0; kc < 6; kc++) {
            bf16x8 ah = *(const bf16x8*)(arh + kc * 32 + quad * 8);
            bf16x8 al = *(const bf16x8*)(arl + kc * 32 + quad * 8);
#pragma unroll
            for (int n = 0; n < 6; n++) {
                bf16x8 bfr = *(const bf16x8*)&Ws[n * 16 + l16][kc * 32 + quad * 8];
                acc[n] = __builtin_amdgcn_mfma_f32_16x16x32_bf16(bfr, al, acc[n], 0, 0, 0);
                acc[n] = __builtin_amdgcn_mfma_f32_16x16x32_bf16(bfr, ah, acc[n], 0, 0, 0);
            }
        }
        int row = m0 + wrow + l16;          // pixel (per-lane, fixed)
        int bb  = row / 784;
        int loc = row - bb * 784;
        bf16* vbase = vtbuf + (size_t)bb * 3 * 64 * 784 + loc;
#pragma unroll
        for (int n = 0; n < 6; n++)
#pragma unroll
            for (int reg = 0; reg < 4; reg++) {
                int col = n0 + n * 16 + quad * 4 + reg;
                int hh = col >> 6, d = col & 63;
                vbase[((size_t)hh * 64 + d) * 784] = (bf16)acc[n][reg];
            }
    } else {
#pragma unroll
        for (int kc = 0; kc < 6; kc++) {
            bf16x8 ah = *(const bf16x8*)(arh + kc * 32 + quad * 8);
            bf16x8 al = *(const bf16x8*)(arl + kc * 32 + quad * 8);
#pragma unroll
            for (int n = 0; n < 6; n++) {
                bf16x8 bfr = *(const bf16x8*)&Ws[n * 16 + l16][kc * 32 + quad * 8];
                acc[n] = __builtin_amdgcn_mfma_f32_16x16x32_bf16(al, bfr, acc[n], 0, 0, 0);
                acc[n] = __builtin_amdgcn_mfma_f32_16x16x32_bf16(ah, bfr, acc[n], 0, 0, 0);
            }
        }
        bf16* outp = (mode == 0) ? qbuf : kbuf;
        // mode 0: 1/8 (head scale) x log2(e) so attn uses raw v_exp_f32
        const float s = (mode == 0) ? 0.18033688f : 1.0f;
#pragma unroll
        for (int reg = 0; reg < 4; reg++) {
            size_t row = m0 + wrow + quad * 4 + reg;
#pragma unroll
            for (int n = 0; n < 6; n++)
                outp[row * 192 + n0 + n * 16 + l16] = (bf16)(acc[n][reg] * s);
        }
    }
}

// ---------------------------------------------------------------------------
// Kernel 3: flash attention. R14 = R12 structure EXACTLY (validated best,
// ~36 us; R13's BK=80 experiment regressed and is reverted) + two VALU trims
// that do not touch the sync structure:
//  - exp2-domain softmax: log2(e) folded into the GEMM's Q scale, so
//    P = v_exp_f32(st - m) directly (saves the per-exp pre-multiply).
//  - defer-rescale (T13, THR=8): when __all(mx - m_run <= 8), keep m_run and
//    skip the 16-mult o_acc rescale + l_run alpha (P bounded by 2^8, safe in
//    bf16/f32; final 1/l_run normalizes). Wave-uniform branch.
// Everything else identical to R12: BK=112 x 7 chunks, Ks double-buffered
// XOR-swizzled DMA, Vts single-buffer DMA with counted-vmcnt visibility,
// Ps[64][64] two-half reuse, 3 blocks/CU (53248 B LDS), waves_per_eu(3,3).
// ---------------------------------------------------------------------------
__global__ __launch_bounds__(256)
__attribute__((amdgpu_waves_per_eu(3, 3)))
void attn3_kernel(const bf16* __restrict__ qb,
                  const bf16* __restrict__ kb,
                  const bf16* __restrict__ vtb,
                  float* __restrict__ out) {
    const int LQ = 3136, LK = 784, C = 192;
    int qt = blockIdx.x, h = blockIdx.y, b = blockIdx.z;

    __shared__ bf16 Ks[2][7168];    // [buf][112][64], XOR-swizzled 16B chunks
    __shared__ bf16 Vts[8192];      // [64][128] phys, XOR-swizzled 16B chunks
    __shared__ bf16 Ps[4096];       // [64][64] logical, XOR-swizzled, 2 halves

    int t    = threadIdx.x;
    int lane = t & 63;
    int wid  = t >> 6;
    int l16  = lane & 15;
    int quad = lane >> 4;
    int wrow = wid * 16;
    int l7   = l16 & 7;
    int qh   = quad >> 1;

    const bf16* kbase  = kb + (size_t)b * LK * C + h * 64;
    const bf16* vtbase = vtb + ((size_t)(b * 3 + h)) * 64 * LK;

    // K DMA source swizzle: dest chunk j = s*64+lane -> row s*8+(lane>>3),
    // physical chunk (lane&7) holds logical chunk (lane&7)^(lane>>3).
    const bf16* ksrc = kbase + (lane >> 3) * C + (((lane & 7) ^ (lane >> 3)) * 8);

    // Vt DMA source offsets (elems): dest chunk j = s*64+lane -> row j>>4,
    // phys chunk j&15 holds logical chunk (j&15)^(row&7); key = logical*8.
    int voff[4];
#pragma unroll
    for (int i = 0; i < 4; i++) {
        int s = wid + 4 * i;
        int j = s * 64 + lane;
        int row = j >> 4;
        int l = (j & 15) ^ (row & 7);
        voff[i] = row * LK + l * 8;
    }

    // prologue: chunk-0 K DMA (14 stripes round-robined over 4 waves)
    for (int s = wid; s < 14; s += 4)
        dma16(ksrc + s * 8 * C, &Ks[0][s * 512]);

    // Q fragments (B operand: n = q = l16, k = d) held in registers
    bf16x8 qfrag[2];
    {
        const bf16* qrow = qb + ((size_t)b * LQ + qt * 64 + wrow + l16) * C + h * 64;
        qfrag[0] = *(const bf16x8*)(qrow + quad * 8);
        qfrag[1] = *(const bf16x8*)(qrow + 32 + quad * 8);
    }

    // per-lane Ks read offsets (elements) for kk=0,1: physical chunk XOR
    int kA0 = l16 * 64 + (((quad    ) ^ l7) * 8);
    int kA1 = l16 * 64 + (((quad + 4) ^ l7) * 8);

    // Ps addressing (elements): row base + chunk-swizzled offsets
    int prow   = (wrow + l16) * 64;          // read base (row stride 64)
    int pwbase = prow + (quad & 1) * 4;      // write base (8B sub-chunk)

    float m_run = -INFINITY, l_run = 0.f;
    f32x4 o_acc[4];
#pragma unroll
    for (int dt = 0; dt < 4; dt++) o_acc[dt] = f32x4{0.f, 0.f, 0.f, 0.f};

    __syncthreads();   // drains prologue DMA -> Ks[0] visible

    for (int c = 0; c < 7; c++) {
        const int cur = c & 1, nxt = cur ^ 1;
        const int j0 = c * 112;

        // 1. Vt[c] DMA: 16 stripes, exactly 4 per wave (oldest in queue)
#pragma unroll
        for (int i = 0; i < 4; i++)
            dma16(vtbase + j0 + voff[i], Vts + (wid + 4 * i) * 512);
        __builtin_amdgcn_sched_barrier(0);   // V issues stay before K issues

        // 2. K[c+1] DMA into the other buffer (4/4/3/3 per wave)
        if (c < 6) {
            const bf16* kn = ksrc + (size_t)(c + 1) * 112 * C;
            for (int s = wid; s < 14; s += 4)
                dma16(kn + s * 8 * C, &Ks[nxt][s * 512]);
        }
        __builtin_amdgcn_sched_barrier(0);   // keep issue groups intact

        // 3. S^T = K Q^T : 7 key-tiles x (K-dim 64 = 2 steps), K from LDS
        f32x4 st[7];
#pragma unroll
        for (int kb7 = 0; kb7 < 7; kb7++) st[kb7] = f32x4{0.f, 0.f, 0.f, 0.f};
#pragma unroll
        for (int kk = 0; kk < 2; kk++) {
            int kA = (kk == 0) ? kA0 : kA1;
#pragma unroll
            for (int kb7 = 0; kb7 < 7; kb7++) {
                bf16x8 afrag = *(const bf16x8*)&Ks[cur][kb7 * 1024 + kA];
                st[kb7] = __builtin_amdgcn_mfma_f32_16x16x32_bf16(afrag, qfrag[kk], st[kb7], 0, 0, 0);
            }
        }

        // 4. online softmax, exp2 domain (log2e folded into Q upstream)
        float mx = -INFINITY;
#pragma unroll
        for (int kb7 = 0; kb7 < 7; kb7++)
#pragma unroll
            for (int r = 0; r < 4; r++) mx = fmaxf(mx, st[kb7][r]);
        mx = fmaxf(mx, __shfl_xor(mx, 16, 64));
        mx = fmaxf(mx, __shfl_xor(mx, 32, 64));

        // defer-rescale (T13): skip m update + o_acc rescale when growth <= 8
        bool defer = __all(mx - m_run <= 8.0f);   // c=0: inf > 8 -> update
        float m_new = defer ? m_run : fmaxf(m_run, mx);

        float rs = 0.f;
        bf16x4 pk[7];                           // static indices only
#pragma unroll
        for (int kb7 = 0; kb7 < 7; kb7++) {
            bf16x4 pv;
#pragma unroll
            for (int r = 0; r < 4; r++) {
                float p = exp2_hw(st[kb7][r] - m_new);
                rs += p;
                pv[r] = (bf16)p;
            }
            pk[kb7] = pv;
        }
        rs += __shfl_xor(rs, 16, 64);
        rs += __shfl_xor(rs, 32, 64);
        if (defer) {
            l_run += rs;
        } else {
            float alpha = exp2_hw(m_run - m_new);   // c=0: 2^(-inf)=0
            l_run = l_run * alpha + rs;
            m_run = m_new;
#pragma unroll
            for (int dt = 0; dt < 4; dt++)
#pragma unroll
                for (int r = 0; r < 4; r++) o_acc[dt][r] *= alpha;
        }

        // 5a. write Ps half0 (keys 0..63): chunk = kb*2+qh, swizzled
#pragma unroll
        for (int kb = 0; kb < 4; kb++)
            *(bf16x4*)&Ps[pwbase + (((kb * 2 + qh) ^ l7) * 8)] = pk[kb];

        // 5b. counted wait: own Vt stripes done when outstanding == own K
        //     count (vmcnt retires in order); raw barrier extends to all waves
        if (c < 6) {
            if (wid < 2) asm volatile("s_waitcnt vmcnt(4)" ::: "memory");
            else         asm volatile("s_waitcnt vmcnt(3)" ::: "memory");
        } else {
            asm volatile("s_waitcnt vmcnt(0)" ::: "memory");
        }
        __builtin_amdgcn_s_barrier();
        __builtin_amdgcn_sched_barrier(0);   // no Vts/Ps reads above this

        // 6a. PV half0: keys 0..63 (global kk 0,1), Vt+P from LDS
#pragma unroll
        for (int kk = 0; kk < 2; kk++) {
            bf16x8 pfrag = *(const bf16x8*)&Ps[prow + (((kk * 4 + quad) ^ l7) * 8)];
#pragma unroll
            for (int dt = 0; dt < 4; dt++) {
                bf16x8 vfrag = *(const bf16x8*)&Vts[(dt * 16 + l16) * 128
                                                   + (((kk * 4 + quad) ^ l7) * 8)];
                o_acc[dt] = __builtin_amdgcn_mfma_f32_16x16x32_bf16(vfrag, pfrag, o_acc[dt], 0, 0, 0);
            }
        }

        // 6b. write Ps half1 (keys 64..111 + zero chunk for pad keys 112..127);
        //     wave-local alias ordering places these after half0's reads
#pragma unroll
        for (int kb = 0; kb < 3; kb++)
            *(bf16x4*)&Ps[pwbase + (((kb * 2 + qh) ^ l7) * 8)] = pk[4 + kb];
        {
            bf16x4 zv = {(bf16)0.f, (bf16)0.f, (bf16)0.f, (bf16)0.f};
            *(bf16x4*)&Ps[pwbase + (((6 + qh) ^ l7) * 8)] = zv;
        }

        // 6c. PV half1: keys 64..127 (global kk 2,3; Ps local kk-2)
#pragma unroll
        for (int kk = 2; kk < 4; kk++) {
            bf16x8 pfrag = *(const bf16x8*)&Ps[prow + ((((kk - 2) * 4 + quad) ^ l7) * 8)];
#pragma unroll
            for (int dt = 0; dt < 4; dt++) {
                bf16x8 vfrag = *(const bf16x8*)&Vts[(dt * 16 + l16) * 128
                                                   + (((kk * 4 + quad) ^ l7) * 8)];
                o_acc[dt] = __builtin_amdgcn_mfma_f32_16x16x32_bf16(vfrag, pfrag, o_acc[dt], 0, 0, 0);
            }
        }

        // 7. end-of-chunk barrier: drains K[c+1] DMA (whole chunk in flight),
        //    orders Ks[cur]/Vts reads vs next chunk's DMA writes.
        __syncthreads();
    }

    // epilogue: lane holds q = l16, d = dt*16 + quad*4 + reg -> float4 stores
    float invl = 1.f / l_run;
    float* ob = out + ((size_t)b * LQ + qt * 64 + wrow + l16) * C + h * 64;
#pragma unroll
    for (int dt = 0; dt < 4; dt++) {
        float4 v4 = {o_acc[dt][0] * invl, o_acc[dt][1] * invl,
                     o_acc[dt][2] * invl, o_acc[dt][3] * invl};
        *(float4*)(ob + dt * 16 + quad * 4) = v4;
    }
}

// ---------------------------------------------------------------------------
extern "C" void kernel_launch(void* const* d_in, const int* in_sizes, int n_in,
                              void* d_out, int out_size, void* d_ws, size_t ws_size,
                              hipStream_t stream) {
    const float* x = (const float*)d_in[0];

    const float* q_dw = (const float*)d_in[1];
    const float* q_scale = (const float*)d_in[2];
    const float* q_bias = (const float*)d_in[3];
    const float* q_mean = (const float*)d_in[4];
    const float* q_var = (const float*)d_in[5];
    const float* q_pw = (const float*)d_in[6];

    const float* k_dw = (const float*)d_in[7];
    const float* k_scale = (const float*)d_in[8];
    const float* k_bias = (const float*)d_in[9];
    const float* k_mean = (const float*)d_in[10];
    const float* k_var = (const float*)d_in[11];
    const float* k_pw = (const float*)d_in[12];

    const float* v_dw = (const float*)d_in[13];
    const float* v_scale = (const float*)d_in[14];
    const float* v_bias = (const float*)d_in[15];
    const float* v_mean = (const float*)d_in[16];
    const float* v_var = (const float*)d_in[17];
    const float* v_pw = (const float*)d_in[18];

    float* out = (float*)d_out;

    // workspace layout (bytes, all 16B aligned)
    char* ws = (char*)d_ws;
    bf16* qhi = (bf16*)(ws);                  // 9,633,792
    bf16* qlo = (bf16*)(ws + 9633792);        // 9,633,792
    bf16* khi = (bf16*)(ws + 19267584);       // 2,408,448
    bf16* klo = (bf16*)(ws + 21676032);       // 2,408,448
    bf16* vhi = (bf16*)(ws + 24084480);       // 2,408,448
    bf16* vlo = (bf16*)(ws + 26492928);       // 2,408,448
    bf16* qbuf = (bf16*)(ws + 28901376);      // 9,633,792
    bf16* kbuf = (bf16*)(ws + 38535168);      // 2,408,448
    bf16* vtbuf = (bf16*)(ws + 40943616);     // 2,408,448
    bf16* wt = (bf16*)(ws + 43352064);        // 221,184

    // stage 1: conv(Q) + conv(K,V) + weight cast, one launch (6312 blocks)
    conv_all_kernel<<<6312, 256, 0, stream>>>(
        x,
        q_dw, q_scale, q_bias, q_mean, q_var,
        k_dw, k_scale, k_bias, k_mean, k_var,
        v_dw, v_scale, v_bias, v_mean, v_var,
        q_pw, k_pw, v_pw,
        qhi, qlo, khi, klo, vhi, vlo, wt);

    // stage 2: all three pointwise GEMMs, one launch (1176 blocks, N split)
    gemm_all_kernel<<<1176, 256, 0, stream>>>(
        qhi, qlo, khi, klo, vhi, vlo, wt, qbuf, kbuf, vtbuf);

    // stage 3: attention (49 q-tiles, 3 heads, 8 batches)
    attn3_kernel<<<dim3(49, 3, 8), 256, 0, stream>>>(qbuf, kbuf, vtbuf, out);
}

// Round 9
// 173.379 us; speedup vs baseline: 1.0631x; 1.0066x over previous
//
#include <hip/hip_runtime.h>
#include <cmath>

#define EPS_BN 1e-5f

typedef __bf16 bf16;
typedef __bf16 bf16x4 __attribute__((ext_vector_type(4)));
typedef __bf16 bf16x8 __attribute__((ext_vector_type(8)));
typedef float  f32x4  __attribute__((ext_vector_type(4)));

// async global->LDS DMA, 16 B per lane, LDS dest = wave-uniform base + lane*16
__device__ __forceinline__ void dma16(const bf16* g, bf16* l) {
    __builtin_amdgcn_global_load_lds(
        (const __attribute__((address_space(1))) void*)g,
        (__attribute__((address_space(3))) void*)l, 16, 0, 0);
}

// raw v_exp_f32: D = 2^S0 (one transcendental op, no pre-multiply)
__device__ __forceinline__ float exp2_hw(float x) {
    float r;
    asm("v_exp_f32 %0, %1" : "=v"(r) : "v"(x));
    return r;
}

// ---------------------------------------------------------------------------
// Kernel 1: all preprocessing elementwise work in one launch. (unchanged R6)
// ---------------------------------------------------------------------------
__global__ __launch_bounds__(256) void conv_all_kernel(
    const float* __restrict__ x,
    const float* __restrict__ qdw, const float* __restrict__ qscale,
    const float* __restrict__ qbias, const float* __restrict__ qmean,
    const float* __restrict__ qvar,
    const float* __restrict__ kdw, const float* __restrict__ kscale,
    const float* __restrict__ kbias, const float* __restrict__ kmean,
    const float* __restrict__ kvar,
    const float* __restrict__ vdw, const float* __restrict__ vscale,
    const float* __restrict__ vbias, const float* __restrict__ vmean,
    const float* __restrict__ vvar,
    const float* __restrict__ qpw, const float* __restrict__ kpw,
    const float* __restrict__ vpw,
    bf16* __restrict__ qhi, bf16* __restrict__ qlo,
    bf16* __restrict__ khi, bf16* __restrict__ klo,
    bf16* __restrict__ vhi, bf16* __restrict__ vlo,
    bf16* __restrict__ wt) {
    const int WW = 56, C = 192;
    int bid = blockIdx.x;

    if (bid < 4704) {
        int idx = bid * 256 + threadIdx.x;
        int p  = idx / 48;
        int c4 = (idx - p * 48) * 4;
        int b  = p / 3136;
        int rem = p - b * 3136;
        int oy = rem / 56;
        int ox = rem - oy * 56;
        const float* xb = x + (size_t)b * 3136 * C;

        float4 sc = *(const float4*)&qscale[c4];
        float4 vr = *(const float4*)&qvar[c4];
        float4 bi = *(const float4*)&qbias[c4];
        float4 mn = *(const float4*)&qmean[c4];
        float aA[4] = {sc.x * rsqrtf(vr.x + EPS_BN), sc.y * rsqrtf(vr.y + EPS_BN),
                       sc.z * rsqrtf(vr.z + EPS_BN), sc.w * rsqrtf(vr.w + EPS_BN)};
        float aB[4] = {bi.x - mn.x * aA[0], bi.y - mn.y * aA[1],
                       bi.z - mn.z * aA[2], bi.w - mn.w * aA[3]};
        float s[4] = {0.f, 0.f, 0.f, 0.f};
#pragma unroll
        for (int ky = 0; ky < 3; ky++) {
            int iy = oy + ky - 1;
            bool yok = (iy >= 0) && (iy < 56);
#pragma unroll
            for (int kx = 0; kx < 3; kx++) {
                int ix = ox + kx - 1;
                if (yok && ix >= 0 && ix < WW) {
                    float4 xv = *(const float4*)&xb[((size_t)iy * WW + ix) * C + c4];
                    float4 wv = *(const float4*)&qdw[(ky * 3 + kx) * C + c4];
                    s[0] += xv.x * wv.x; s[1] += xv.y * wv.y;
                    s[2] += xv.z * wv.z; s[3] += xv.w * wv.w;
                }
            }
        }
        bf16x4 hv, lv;
#pragma unroll
        for (int j = 0; j < 4; j++) {
            float av = s[j] * aA[j] + aB[j];
            bf16 hh = (bf16)av;
            hv[j] = hh;
            lv[j] = (bf16)(av - (float)hh);
        }
        *(bf16x4*)&qhi[(size_t)p * C + c4] = hv;
        *(bf16x4*)&qlo[(size_t)p * C + c4] = lv;
    } else if (bid < 5880) {
        int idx = (bid - 4704) * 256 + threadIdx.x;
        int p  = idx / 48;
        int c4 = (idx - p * 48) * 4;
        int b  = p / 784;
        int rem = p - b * 784;
        int oy = rem / 28;
        int ox = rem - oy * 28;
        const float* xb = x + (size_t)b * 3136 * C;

        float ks[4] = {0.f, 0.f, 0.f, 0.f};
        float vs[4] = {0.f, 0.f, 0.f, 0.f};
#pragma unroll
        for (int ky = 0; ky < 3; ky++) {
            int iy = oy * 2 + ky;
            bool yok = iy < 56;
#pragma unroll
            for (int kx = 0; kx < 3; kx++) {
                int ix = ox * 2 + kx;
                if (yok && ix < WW) {
                    float4 xv = *(const float4*)&xb[((size_t)iy * WW + ix) * C + c4];
                    float4 kw = *(const float4*)&kdw[(ky * 3 + kx) * C + c4];
                    float4 vw = *(const float4*)&vdw[(ky * 3 + kx) * C + c4];
                    ks[0] += xv.x * kw.x; ks[1] += xv.y * kw.y;
                    ks[2] += xv.z * kw.z; ks[3] += xv.w * kw.w;
                    vs[0] += xv.x * vw.x; vs[1] += xv.y * vw.y;
                    vs[2] += xv.z * vw.z; vs[3] += xv.w * vw.w;
                }
            }
        }
        float4 ksc = *(const float4*)&kscale[c4];
        float4 kvr = *(const float4*)&kvar[c4];
        float4 kbi = *(const float4*)&kbias[c4];
        float4 kmn = *(const float4*)&kmean[c4];
        float4 vsc = *(const float4*)&vscale[c4];
        float4 vvr = *(const float4*)&vvar[c4];
        float4 vbi = *(const float4*)&vbias[c4];
        float4 vmn = *(const float4*)&vmean[c4];
        float kA[4] = {ksc.x * rsqrtf(kvr.x + EPS_BN), ksc.y * rsqrtf(kvr.y + EPS_BN),
                       ksc.z * rsqrtf(kvr.z + EPS_BN), ksc.w * rsqrtf(kvr.w + EPS_BN)};
        float kB[4] = {kbi.x - kmn.x * kA[0], kbi.y - kmn.y * kA[1],
                       kbi.z - kmn.z * kA[2], kbi.w - kmn.w * kA[3]};
        float vA[4] = {vsc.x * rsqrtf(vvr.x + EPS_BN), vsc.y * rsqrtf(vvr.y + EPS_BN),
                       vsc.z * rsqrtf(vvr.z + EPS_BN), vsc.w * rsqrtf(vvr.w + EPS_BN)};
        float vB[4] = {vbi.x - vmn.x * vA[0], vbi.y - vmn.y * vA[1],
                       vbi.z - vmn.z * vA[2], vbi.w - vmn.w * vA[3]};
        bf16x4 kh, kl, vh, vl;
#pragma unroll
        for (int j = 0; j < 4; j++) {
            float kf = ks[j] * kA[j] + kB[j];
            float vf = vs[j] * vA[j] + vB[j];
            bf16 h1 = (bf16)kf; kh[j] = h1; kl[j] = (bf16)(kf - (float)h1);
            bf16 h2 = (bf16)vf; vh[j] = h2; vl[j] = (bf16)(vf - (float)h2);
        }
        *(bf16x4*)&khi[(size_t)p * C + c4] = kh;
        *(bf16x4*)&klo[(size_t)p * C + c4] = kl;
        *(bf16x4*)&vhi[(size_t)p * C + c4] = vh;
        *(bf16x4*)&vlo[(size_t)p * C + c4] = vl;
    } else {
        int idx = (bid - 5880) * 256 + threadIdx.x;
        if (idx < 3 * 36864) {
            int mat = idx / 36864, r = idx % 36864;
            int n = r / 192, k = r - n * 192;
            const float* src = (mat == 0) ? qpw : (mat == 1) ? kpw : vpw;
            wt[idx] = (bf16)src[k * 192 + n];
        }
    }
}

// ---------------------------------------------------------------------------
// Kernel 2: pointwise GEMMs, N split in two, Ws[96][200] = 38.4 KB.
// (unchanged R14: mode-0 scale folds log2e; mode-2 swapped-operand MFMA for
// contiguous vtbuf stores)
// ---------------------------------------------------------------------------
__global__ __launch_bounds__(256) void gemm_all_kernel(
    const bf16* __restrict__ qhi, const bf16* __restrict__ qlo,
    const bf16* __restrict__ khi, const bf16* __restrict__ klo,
    const bf16* __restrict__ vhi, const bf16* __restrict__ vlo,
    const bf16* __restrict__ wt,
    bf16* __restrict__ qbuf, bf16* __restrict__ kbuf, bf16* __restrict__ vtbuf) {
    __shared__ bf16 Ws[96][200];
    int t = threadIdx.x;
    int bid = blockIdx.x;

    int mode, mt, nh;
    const bf16 *Ahi, *Alo, *Wsrc;
    if (bid < 784)      { mode = 0; mt = bid >> 1;         nh = bid & 1;
                          Ahi = qhi; Alo = qlo; Wsrc = wt; }
    else if (bid < 980) { mode = 1; int r = bid - 784; mt = r >> 1; nh = r & 1;
                          Ahi = khi; Alo = klo; Wsrc = wt + 36864; }
    else                { mode = 2; int r = bid - 980; mt = r >> 1; nh = r & 1;
                          Ahi = vhi; Alo = vlo; Wsrc = wt + 73728; }
    int n0 = nh * 96;

#pragma unroll
    for (int it = 0; it < 9; it++) {
        int idx = it * 256 + t;
        int n = idx / 24, ck = idx - n * 24;
        *(uint4*)&Ws[n][ck * 8] = *(const uint4*)&Wsrc[(size_t)(n0 + n) * 192 + ck * 8];
    }
    __syncthreads();

    int lane = t & 63, wid = t >> 6;
    int l16 = lane & 15, quad = lane >> 4;
    int wrow = wid * 16;
    int m0 = mt * 64;

    f32x4 acc[6];
#pragma unroll
    for (int n = 0; n < 6; n++) acc[n] = f32x4{0.f, 0.f, 0.f, 0.f};

    const bf16* arh = Ahi + (size_t)(m0 + wrow + l16) * 192;
    const bf16* arl = Alo + (size_t)(m0 + wrow + l16) * 192;

    if (mode == 2) {
        // swapped operands: D[w][pixel] — lane holds pixel = wrow+l16,
        // weight col = n*16 + quad*4 + reg
#pragma unroll
        for (int kc = 0; kc < 6; kc++) {
            bf16x8 ah = *(const bf16x8*)(arh + kc * 32 + quad * 8);
            bf16x8 al = *(const bf16x8*)(arl + kc * 32 + quad * 8);
#pragma unroll
            for (int n = 0; n < 6; n++) {
                bf16x8 bfr = *(const bf16x8*)&Ws[n * 16 + l16][kc * 32 + quad * 8];
                acc[n] = __builtin_amdgcn_mfma_f32_16x16x32_bf16(bfr, al, acc[n], 0, 0, 0);
                acc[n] = __builtin_amdgcn_mfma_f32_16x16x32_bf16(bfr, ah, acc[n], 0, 0, 0);
            }
        }
        int row = m0 + wrow + l16;          // pixel (per-lane, fixed)
        int bb  = row / 784;
        int loc = row - bb * 784;
        bf16* vbase = vtbuf + (size_t)bb * 3 * 64 * 784 + loc;
#pragma unroll
        for (int n = 0; n < 6; n++)
#pragma unroll
            for (int reg = 0; reg < 4; reg++) {
                int col = n0 + n * 16 + quad * 4 + reg;
                int hh = col >> 6, d = col & 63;
                vbase[((size_t)hh * 64 + d) * 784] = (bf16)acc[n][reg];
            }
    } else {
#pragma unroll
        for (int kc = 0; kc < 6; kc++) {
            bf16x8 ah = *(const bf16x8*)(arh + kc * 32 + quad * 8);
            bf16x8 al = *(const bf16x8*)(arl + kc * 32 + quad * 8);
#pragma unroll
            for (int n = 0; n < 6; n++) {
                bf16x8 bfr = *(const bf16x8*)&Ws[n * 16 + l16][kc * 32 + quad * 8];
                acc[n] = __builtin_amdgcn_mfma_f32_16x16x32_bf16(al, bfr, acc[n], 0, 0, 0);
                acc[n] = __builtin_amdgcn_mfma_f32_16x16x32_bf16(ah, bfr, acc[n], 0, 0, 0);
            }
        }
        bf16* outp = (mode == 0) ? qbuf : kbuf;
        // mode 0: 1/8 (head scale) x log2(e) so attn uses raw v_exp_f32
        const float s = (mode == 0) ? 0.18033688f : 1.0f;
#pragma unroll
        for (int reg = 0; reg < 4; reg++) {
            size_t row = m0 + wrow + quad * 4 + reg;
#pragma unroll
            for (int n = 0; n < 6; n++)
                outp[row * 192 + n0 + n * 16 + l16] = (bf16)(acc[n][reg] * s);
        }
    }
}

// ---------------------------------------------------------------------------
// Kernel 3: flash attention. R16: 8-wave blocks, 128 q-rows/block.
// R14's profile: latency-bound with two structural costs — 1176 blocks at
// 3/CU = 1.53 scheduling rounds (400-block tail), and each (b,h)'s K/V
// staged by 49 blocks (30 DMA stripes + 2 barriers per chunk serve only
// 64 q-rows). R16 halves both: 512 threads (8 waves) process 128 q-rows
// sharing one staging pipeline -> per-work barrier/DMA cost halves; grid
// (25,3,8)=600 blocks; LDS = Ks 28672 + Vts 16384 + Ps[128][64] 16384
// = 61440 B -> 2 blocks/CU = 16 waves/CU = 4 waves/SIMD SUSTAINED (vs 3),
// ~1.17 rounds (vs 1.53). Sync skeleton identical to R12/R14 (validated):
// V DMA issued first (2 stripes/wave), K[c+1] second (2/2/2/2/2/2/1/1),
// counted s_waitcnt vmcnt(ownK) + raw s_barrier + sched_barrier before PV,
// K never drained mid-chunk, one full drain at chunk end. R14 trims kept
// (exp2-domain softmax, defer-rescale THR=8).
// qt=24: waves 4..7 have no valid q-rows — they compute garbage (Q reads
// spill <=24 KB into adjacent allocated kbuf; finite or NaN, contained in
// per-wave registers and their own Ps rows) and skip the epilogue store.
// All barriers remain non-divergent.
// ---------------------------------------------------------------------------
__global__ __launch_bounds__(512)
__attribute__((amdgpu_waves_per_eu(4, 4)))
void attn3_kernel(const bf16* __restrict__ qb,
                  const bf16* __restrict__ kb,
                  const bf16* __restrict__ vtb,
                  float* __restrict__ out) {
    const int LQ = 3136, LK = 784, C = 192;
    int qt = blockIdx.x, h = blockIdx.y, b = blockIdx.z;

    __shared__ bf16 Ks[2][7168];    // [buf][112][64], XOR-swizzled 16B chunks
    __shared__ bf16 Vts[8192];      // [64][128] phys, XOR-swizzled 16B chunks
    __shared__ bf16 Ps[8192];       // [128][64] logical, XOR-swizzled, 2 halves

    int t    = threadIdx.x;
    int lane = t & 63;
    int wid  = t >> 6;              // 0..7
    int l16  = lane & 15;
    int quad = lane >> 4;
    int wrow = wid * 16;            // 0..112
    int l7   = l16 & 7;
    int qh   = quad >> 1;

    const bf16* kbase  = kb + (size_t)b * LK * C + h * 64;
    const bf16* vtbase = vtb + ((size_t)(b * 3 + h)) * 64 * LK;

    // K DMA source swizzle: dest chunk j = s*64+lane -> row s*8+(lane>>3),
    // physical chunk (lane&7) holds logical chunk (lane&7)^(lane>>3).
    const bf16* ksrc = kbase + (lane >> 3) * C + (((lane & 7) ^ (lane >> 3)) * 8);

    // Vt DMA source offsets (elems): dest chunk j = s*64+lane -> row j>>4,
    // phys chunk j&15 holds logical chunk (j&15)^(row&7); key = logical*8.
    // 16 stripes over 8 waves: s = wid, wid+8.
    int voff[2];
#pragma unroll
    for (int i = 0; i < 2; i++) {
        int s = wid + 8 * i;
        int j = s * 64 + lane;
        int row = j >> 4;
        int l = (j & 15) ^ (row & 7);
        voff[i] = row * LK + l * 8;
    }

    // prologue: chunk-0 K DMA (14 stripes over 8 waves: 2/2/2/2/2/2/1/1)
    for (int s = wid; s < 14; s += 8)
        dma16(ksrc + s * 8 * C, &Ks[0][s * 512]);

    // Q fragments (B operand: n = q = l16, k = d) held in registers
    bf16x8 qfrag[2];
    {
        const bf16* qrow = qb + ((size_t)b * LQ + qt * 128 + wrow + l16) * C + h * 64;
        qfrag[0] = *(const bf16x8*)(qrow + quad * 8);
        qfrag[1] = *(const bf16x8*)(qrow + 32 + quad * 8);
    }
    bool qvalid = (qt < 24) || (wid < 4);   // qt=24: only rows 3072..3135

    // per-lane Ks read offsets (elements) for kk=0,1: physical chunk XOR
    int kA0 = l16 * 64 + (((quad    ) ^ l7) * 8);
    int kA1 = l16 * 64 + (((quad + 4) ^ l7) * 8);

    // Ps addressing (elements): row base + chunk-swizzled offsets
    int prow   = (wrow + l16) * 64;          // read base (row stride 64)
    int pwbase = prow + (quad & 1) * 4;      // write base (8B sub-chunk)

    float m_run = -INFINITY, l_run = 0.f;
    f32x4 o_acc[4];
#pragma unroll
    for (int dt = 0; dt < 4; dt++) o_acc[dt] = f32x4{0.f, 0.f, 0.f, 0.f};

    __syncthreads();   // drains prologue DMA -> Ks[0] visible

    for (int c = 0; c < 7; c++) {
        const int cur = c & 1, nxt = cur ^ 1;
        const int j0 = c * 112;

        // 1. Vt[c] DMA: 16 stripes, exactly 2 per wave (oldest in queue)
#pragma unroll
        for (int i = 0; i < 2; i++)
            dma16(vtbase + j0 + voff[i], Vts + (wid + 8 * i) * 512);
        __builtin_amdgcn_sched_barrier(0);   // V issues stay before K issues

        // 2. K[c+1] DMA into the other buffer (2/2/2/2/2/2/1/1 per wave)
        if (c < 6) {
            const bf16* kn = ksrc + (size_t)(c + 1) * 112 * C;
            for (int s = wid; s < 14; s += 8)
                dma16(kn + s * 8 * C, &Ks[nxt][s * 512]);
        }
        __builtin_amdgcn_sched_barrier(0);   // keep issue groups intact

        // 3. S^T = K Q^T : 7 key-tiles x (K-dim 64 = 2 steps), K from LDS
        f32x4 st[7];
#pragma unroll
        for (int kb7 = 0; kb7 < 7; kb7++) st[kb7] = f32x4{0.f, 0.f, 0.f, 0.f};
#pragma unroll
        for (int kk = 0; kk < 2; kk++) {
            int kA = (kk == 0) ? kA0 : kA1;
#pragma unroll
            for (int kb7 = 0; kb7 < 7; kb7++) {
                bf16x8 afrag = *(const bf16x8*)&Ks[cur][kb7 * 1024 + kA];
                st[kb7] = __builtin_amdgcn_mfma_f32_16x16x32_bf16(afrag, qfrag[kk], st[kb7], 0, 0, 0);
            }
        }

        // 4. online softmax, exp2 domain (log2e folded into Q upstream)
        float mx = -INFINITY;
#pragma unroll
        for (int kb7 = 0; kb7 < 7; kb7++)
#pragma unroll
            for (int r = 0; r < 4; r++) mx = fmaxf(mx, st[kb7][r]);
        mx = fmaxf(mx, __shfl_xor(mx, 16, 64));
        mx = fmaxf(mx, __shfl_xor(mx, 32, 64));

        // defer-rescale (T13): skip m update + o_acc rescale when growth <= 8
        bool defer = __all(mx - m_run <= 8.0f);   // c=0: inf > 8 -> update
        float m_new = defer ? m_run : fmaxf(m_run, mx);

        float rs = 0.f;
        bf16x4 pk[7];                           // static indices only
#pragma unroll
        for (int kb7 = 0; kb7 < 7; kb7++) {
            bf16x4 pv;
#pragma unroll
            for (int r = 0; r < 4; r++) {
                float p = exp2_hw(st[kb7][r] - m_new);
                rs += p;
                pv[r] = (bf16)p;
            }
            pk[kb7] = pv;
        }
        rs += __shfl_xor(rs, 16, 64);
        rs += __shfl_xor(rs, 32, 64);
        if (defer) {
            l_run += rs;
        } else {
            float alpha = exp2_hw(m_run - m_new);   // c=0: 2^(-inf)=0
            l_run = l_run * alpha + rs;
            m_run = m_new;
#pragma unroll
            for (int dt = 0; dt < 4; dt++)
#pragma unroll
                for (int r = 0; r < 4; r++) o_acc[dt][r] *= alpha;
        }

        // 5a. write Ps half0 (keys 0..63): chunk = kb*2+qh, swizzled
#pragma unroll
        for (int kb = 0; kb < 4; kb++)
            *(bf16x4*)&Ps[pwbase + (((kb * 2 + qh) ^ l7) * 8)] = pk[kb];

        // 5b. counted wait: own Vt stripes done when outstanding == own K
        //     count (vmcnt retires in order); raw barrier extends to all waves
        if (c < 6) {
            if (wid < 6) asm volatile("s_waitcnt vmcnt(2)" ::: "memory");
            else         asm volatile("s_waitcnt vmcnt(1)" ::: "memory");
        } else {
            asm volatile("s_waitcnt vmcnt(0)" ::: "memory");
        }
        __builtin_amdgcn_s_barrier();
        __builtin_amdgcn_sched_barrier(0);   // no Vts/Ps reads above this

        // 6a. PV half0: keys 0..63 (global kk 0,1), Vt+P from LDS
#pragma unroll
        for (int kk = 0; kk < 2; kk++) {
            bf16x8 pfrag = *(const bf16x8*)&Ps[prow + (((kk * 4 + quad) ^ l7) * 8)];
#pragma unroll
            for (int dt = 0; dt < 4; dt++) {
                bf16x8 vfrag = *(const bf16x8*)&Vts[(dt * 16 + l16) * 128
                                                   + (((kk * 4 + quad) ^ l7) * 8)];
                o_acc[dt] = __builtin_amdgcn_mfma_f32_16x16x32_bf16(vfrag, pfrag, o_acc[dt], 0, 0, 0);
            }
        }

        // 6b. write Ps half1 (keys 64..111 + zero chunk for pad keys 112..127);
        //     wave-local alias ordering places these after half0's reads
#pragma unroll
        for (int kb = 0; kb < 3; kb++)
            *(bf16x4*)&Ps[pwbase + (((kb * 2 + qh) ^ l7) * 8)] = pk[4 + kb];
        {
            bf16x4 zv = {(bf16)0.f, (bf16)0.f, (bf16)0.f, (bf16)0.f};
            *(bf16x4*)&Ps[pwbase + (((6 + qh) ^ l7) * 8)] = zv;
        }

        // 6c. PV half1: keys 64..127 (global kk 2,3; Ps local kk-2)
#pragma unroll
        for (int kk = 2; kk < 4; kk++) {
            bf16x8 pfrag = *(const bf16x8*)&Ps[prow + ((((kk - 2) * 4 + quad) ^ l7) * 8)];
#pragma unroll
            for (int dt = 0; dt < 4; dt++) {
                bf16x8 vfrag = *(const bf16x8*)&Vts[(dt * 16 + l16) * 128
                                                   + (((kk * 4 + quad) ^ l7) * 8)];
                o_acc[dt] = __builtin_amdgcn_mfma_f32_16x16x32_bf16(vfrag, pfrag, o_acc[dt], 0, 0, 0);
            }
        }

        // 7. end-of-chunk barrier: drains K[c+1] DMA (whole chunk in flight),
        //    orders Ks[cur]/Vts reads vs next chunk's DMA writes.
        __syncthreads();
    }

    // epilogue: lane holds q = l16, d = dt*16 + quad*4 + reg -> float4 stores
    if (qvalid) {
        float invl = 1.f / l_run;
        float* ob = out + ((size_t)b * LQ + qt * 128 + wrow + l16) * C + h * 64;
#pragma unroll
        for (int dt = 0; dt < 4; dt++) {
            float4 v4 = {o_acc[dt][0] * invl, o_acc[dt][1] * invl,
                         o_acc[dt][2] * invl, o_acc[dt][3] * invl};
            *(float4*)(ob + dt * 16 + quad * 4) = v4;
        }
    }
}

// ---------------------------------------------------------------------------
extern "C" void kernel_launch(void* const* d_in, const int* in_sizes, int n_in,
                              void* d_out, int out_size, void* d_ws, size_t ws_size,
                              hipStream_t stream) {
    const float* x = (const float*)d_in[0];

    const float* q_dw = (const float*)d_in[1];
    const float* q_scale = (const float*)d_in[2];
    const float* q_bias = (const float*)d_in[3];
    const float* q_mean = (const float*)d_in[4];
    const float* q_var = (const float*)d_in[5];
    const float* q_pw = (const float*)d_in[6];

    const float* k_dw = (const float*)d_in[7];
    const float* k_scale = (const float*)d_in[8];
    const float* k_bias = (const float*)d_in[9];
    const float* k_mean = (const float*)d_in[10];
    const float* k_var = (const float*)d_in[11];
    const float* k_pw = (const float*)d_in[12];

    const float* v_dw = (const float*)d_in[13];
    const float* v_scale = (const float*)d_in[14];
    const float* v_bias = (const float*)d_in[15];
    const float* v_mean = (const float*)d_in[16];
    const float* v_var = (const float*)d_in[17];
    const float* v_pw = (const float*)d_in[18];

    float* out = (float*)d_out;

    // workspace layout (bytes, all 16B aligned)
    char* ws = (char*)d_ws;
    bf16* qhi = (bf16*)(ws);                  // 9,633,792
    bf16* qlo = (bf16*)(ws + 9633792);        // 9,633,792
    bf16* khi = (bf16*)(ws + 19267584);       // 2,408,448
    bf16* klo = (bf16*)(ws + 21676032);       // 2,408,448
    bf16* vhi = (bf16*)(ws + 24084480);       // 2,408,448
    bf16* vlo = (bf16*)(ws + 26492928);       // 2,408,448
    bf16* qbuf = (bf16*)(ws + 28901376);      // 9,633,792
    bf16* kbuf = (bf16*)(ws + 38535168);      // 2,408,448
    bf16* vtbuf = (bf16*)(ws + 40943616);     // 2,408,448
    bf16* wt = (bf16*)(ws + 43352064);        // 221,184

    // stage 1: conv(Q) + conv(K,V) + weight cast, one launch (6312 blocks)
    conv_all_kernel<<<6312, 256, 0, stream>>>(
        x,
        q_dw, q_scale, q_bias, q_mean, q_var,
        k_dw, k_scale, k_bias, k_mean, k_var,
        v_dw, v_scale, v_bias, v_mean, v_var,
        q_pw, k_pw, v_pw,
        qhi, qlo, khi, klo, vhi, vlo, wt);

    // stage 2: all three pointwise GEMMs, one launch (1176 blocks, N split)
    gemm_all_kernel<<<1176, 256, 0, stream>>>(
        qhi, qlo, khi, klo, vhi, vlo, wt, qbuf, kbuf, vtbuf);

    // stage 3: attention (25 q-tiles of 128 rows, 3 heads, 8 batches)
    attn3_kernel<<<dim3(25, 3, 8), 512, 0, stream>>>(qbuf, kbuf, vtbuf, out);
}